// Round 2
// baseline (1745.438 us; speedup 1.0000x reference)
//
#include <hip/hip_runtime.h>
#include <cstdint>

// LSTM: B=1024, T=336, I=64, H=256, gates 4H=1024, K = I+H = 320.
// 32 batch-groups x 8 member-WGs = 256 WGs (1/CU), persistent over all T.
// R7: exchange locality without trusting placement or cache-bit semantics:
//  (1) blocks regroup at runtime by measured XCC_ID + arrival rank, so each
//      8-member group is same-XCD whenever per-XCD block counts allow;
//      XCC_ID is only a performance hint (garbage ids -> arbitrary groups).
//  (2) each group runs a bounded magic-tag PROBE using the exact sc0-only
//      store/load pair of the fast path. Only a group whose 8 members all
//      see all 8 producers enables sc0 (L2-local) exchange; otherwise it
//      uses the proven sc0+sc1 device path. A cross-XCD pair cannot pass
//      the probe (producer's store stays dirty in its remote L2; consumer
//      re-hits its own stale clean line), so misdetection degrades to
//      baseline speed, never to corruption.
//  (3) keeps R6's audited-clean secondary fixes: x_t prefetched one step
//      ahead; VSTRIDE 336->344 (688 B rows: 2-way LDS conflict, free).

#define NGROUP  32
#define BATCH_G 32
#define T_STEPS 336
#define I_DIM   64
#define H_DIM   256
#define VSTRIDE 344   // ushorts per staged row: K=320 + 24 pad (688 B, 16B-aligned)
#define PAIRS   128   // h-pairs per batch row (256 cols / 2)
#define OUT_HALF 262144  // 1024*256
#define MAGIC   0x7F7F7F7Fu   // probe tag; main-loop tags are 1..336

typedef __attribute__((ext_vector_type(8))) __bf16 bf16x8;
typedef __attribute__((ext_vector_type(8))) unsigned short ushort8_t;
typedef __attribute__((ext_vector_type(4))) float f32x4;
typedef __attribute__((ext_vector_type(4))) unsigned uint32x4;
typedef __attribute__((ext_vector_type(2))) unsigned uint32x2;

__device__ inline unsigned short f2bf(float f) {
  unsigned u = __builtin_bit_cast(unsigned, f);
  return (unsigned short)((u + 0x7fffu + ((u >> 16) & 1u)) >> 16);
}
__device__ inline float sigf(float x) { return 1.f / (1.f + __expf(-x)); }
__device__ inline float tanhfast(float x) { return 1.f - 2.f / (1.f + __expf(2.f * x)); }

// 4 concurrent coherent 16B loads (8 tagged pairs = 64B contiguous), one round trip.
// DEV=true: device scope (sc0 sc1, cross-XCD safe). DEV=false: XCD-local (sc0,
// L1-bypass; only used when the group passed the runtime coherence probe).
template<bool DEV>
__device__ inline void ld4_tagged(const uint32x2* p, uint32x4& a, uint32x4& b,
                                  uint32x4& c, uint32x4& d) {
  if constexpr (DEV) {
    asm volatile(
        "global_load_dwordx4 %0, %4, off sc0 sc1\n\t"
        "global_load_dwordx4 %1, %5, off sc0 sc1\n\t"
        "global_load_dwordx4 %2, %6, off sc0 sc1\n\t"
        "global_load_dwordx4 %3, %7, off sc0 sc1\n\t"
        "s_waitcnt vmcnt(0)"
        : "=&v"(a), "=&v"(b), "=&v"(c), "=&v"(d)
        : "v"(p), "v"(p + 2), "v"(p + 4), "v"(p + 6)
        : "memory");
  } else {
    asm volatile(
        "global_load_dwordx4 %0, %4, off sc0\n\t"
        "global_load_dwordx4 %1, %5, off sc0\n\t"
        "global_load_dwordx4 %2, %6, off sc0\n\t"
        "global_load_dwordx4 %3, %7, off sc0\n\t"
        "s_waitcnt vmcnt(0)"
        : "=&v"(a), "=&v"(b), "=&v"(c), "=&v"(d)
        : "v"(p), "v"(p + 2), "v"(p + 4), "v"(p + 6)
        : "memory");
  }
}
template<bool DEV>
__device__ inline void st_pair(uint32x2* p, uint32x2 v) {
  if constexpr (DEV) {
    asm volatile("global_store_dwordx2 %0, %1, off sc0 sc1" :: "v"(p), "v"(v) : "memory");
  } else {
    asm volatile("global_store_dwordx2 %0, %1, off sc0" :: "v"(p), "v"(v) : "memory");
  }
}

// Poll partner slice until tag matches, then scatter into LDS staging rows.
template<bool DEV>
__device__ inline void stage_h(const uint32x2* hsrc, unsigned tag, unsigned short* hdst) {
  uint32x4 A, Bv, C, D;
  int it = 0;
  for (;;) {
    ld4_tagged<DEV>(hsrc, A, Bv, C, D);
    bool ok = (A[0] == tag) & (A[2] == tag) & (Bv[0] == tag) & (Bv[2] == tag) &
              (C[0] == tag) & (C[2] == tag) & (D[0] == tag) & (D[2] == tag);
    if (ok) break;
    if (++it > (1 << 17)) break;   // safety valve vs. hang
    __builtin_amdgcn_s_sleep(1);
  }
  *(unsigned*)(hdst + 0 * VSTRIDE) = A[1];
  *(unsigned*)(hdst + 1 * VSTRIDE) = A[3];
  *(unsigned*)(hdst + 2 * VSTRIDE) = Bv[1];
  *(unsigned*)(hdst + 3 * VSTRIDE) = Bv[3];
  *(unsigned*)(hdst + 4 * VSTRIDE) = C[1];
  *(unsigned*)(hdst + 5 * VSTRIDE) = C[3];
  *(unsigned*)(hdst + 6 * VSTRIDE) = D[1];
  *(unsigned*)(hdst + 7 * VSTRIDE) = D[3];
}

// Bounded sc0-only poll for the coherence probe. Returns true iff all 8
// magic-tagged pairs became visible via the fast path.
__device__ inline bool probe_poll(const uint32x2* p) {
  uint32x4 A, Bv, C, D;
  for (int it = 0; it < 512; ++it) {
    ld4_tagged<false>(p, A, Bv, C, D);
    bool ok = (A[0] == MAGIC) & (A[2] == MAGIC) & (Bv[0] == MAGIC) & (Bv[2] == MAGIC) &
              (C[0] == MAGIC) & (C[2] == MAGIC) & (D[0] == MAGIC) & (D[2] == MAGIC);
    if (ok) return true;
    __builtin_amdgcn_s_sleep(1);
  }
  return false;
}

__global__ __launch_bounds__(512, 2) void lstm_persistent(
    const float* __restrict__ x, const float* __restrict__ W_ih,
    const float* __restrict__ W_hh, const float* __restrict__ b_ih,
    const float* __restrict__ b_hh, float* __restrict__ out,
    uint32x2* __restrict__ hbuf, unsigned* __restrict__ xtab)
{
  __shared__ __align__(16) unsigned short v_lds[2][BATCH_G * VSTRIDE];
  __shared__ int s_same, s_ok;
  __shared__ unsigned s_cnt[8], s_xcd, s_rank;

  const int tid  = threadIdx.x;
  const int wv   = tid >> 6;          // wave 0..7
  const int l    = tid & 63;
  const int l15  = l & 15, quad = l >> 4;
  const int rg   = wv >> 1;           // row-group 0..3: local cols [8*rg, +8)
  const int bh   = wv & 1;            // batch half: [16*bh, +16)

  unsigned* cnt   = xtab;       // [0..7]   per-XCD arrival counters
  unsigned* vslot = xtab + 8;   // [8..263] per-(gid,mid) probe verdict slots

  // ---- placement discovery: XCC id (hint only) + arrival rank ----
  if (tid == 0) {
    unsigned xcd = (unsigned)__builtin_amdgcn_s_getreg((31u << 11) | 20u) & 7u;
    s_xcd  = xcd;
    s_rank = __hip_atomic_fetch_add(&cnt[xcd], 1u, __ATOMIC_ACQ_REL,
                                    __HIP_MEMORY_SCOPE_AGENT);
    // all 256 blocks are co-resident (1 WG/CU, bounds allow 2) -> this settles
    for (int itr = 0; itr < (1 << 26); ++itr) {
      unsigned tot = 0;
      for (int xx = 0; xx < 8; ++xx)
        tot += __hip_atomic_load(&cnt[xx], __ATOMIC_ACQUIRE, __HIP_MEMORY_SCOPE_AGENT);
      if (tot >= 256u) break;
      __builtin_amdgcn_s_sleep(4);
    }
    for (int xx = 0; xx < 8; ++xx)
      s_cnt[xx] = __hip_atomic_load(&cnt[xx], __ATOMIC_ACQUIRE, __HIP_MEMORY_SCOPE_AGENT);
  }
  __syncthreads();

  // ---- derive (gid, mid): same-XCD groups of 8 where counts allow;
  //      leftovers form deterministic mixed groups (probe will reject). ----
  int gid, mid;
  {
    const unsigned xcd = s_xcd, rank = s_rank;
    unsigned prefFull = 0, prefLeft = 0, totalFull = 0;
    for (unsigned xx = 0; xx < 8; ++xx) {
      unsigned n = s_cnt[xx], f = n >> 3;
      totalFull += f;
      if (xx < xcd) { prefFull += f; prefLeft += n - (f << 3); }
    }
    const unsigned fullx = (s_cnt[xcd] >> 3) << 3;
    if (rank < fullx) {
      gid = (int)(prefFull + (rank >> 3));
      mid = (int)(rank & 7u);
    } else {
      unsigned li = prefLeft + (rank - fullx);
      gid = (int)(totalFull + (li >> 3));
      mid = (int)(li & 7u);
    }
  }

  // ---- A-fragments: local row r16 = 4*col + gate ----
  bf16x8 afrag[2][10];
#pragma unroll
  for (int rt = 0; rt < 2; ++rt) {
    int grow = (l15 & 3) * H_DIM + mid * 32 + rg * 8 + rt * 4 + (l15 >> 2);
    const float* wih_row = W_ih + (long)grow * I_DIM;
    const float* whh_row = W_hh + (long)grow * H_DIM;
#pragma unroll
    for (int kt = 0; kt < 10; ++kt) {
      int kbase = kt * 32 + quad * 8;
      ushort8_t a;
#pragma unroll
      for (int e = 0; e < 8; ++e) {
        int k = kbase + e;
        float v = (k < I_DIM) ? wih_row[k] : whh_row[k - I_DIM];
        a[e] = f2bf(v);
      }
      afrag[rt][kt] = __builtin_bit_cast(bf16x8, a);
    }
  }

  // ---- bias as acc-init: lane's cell = (col = rg*8+rt*4+quad, batch = bh*16+l15) ----
  f32x4 bias[2];
#pragma unroll
  for (int rt = 0; rt < 2; ++rt) {
#pragma unroll
    for (int g = 0; g < 4; ++g) {
      int grow = g * H_DIM + mid * 32 + rg * 8 + rt * 4 + quad;
      bias[rt][g] = b_ih[grow] + b_hh[grow];
    }
  }

  const int batch = bh * 16 + l15;    // 0..31 within group
  float c_reg[2] = {0.f, 0.f};
  float h_keep[2];

  // ---- x staging: 16 threads per batch row ----
  const int b_stage = tid >> 4;          // 0..31
  const int x_i4    = (tid & 15) * 4;    // 4 floats of x
  const float* xrow = x + ((long)(gid * 32 + b_stage)) * T_STEPS * I_DIM + x_i4;

  // ---- h staging (consumer): thread owns pair p_ld, batches b0_ld..b0_ld+7
  //      = 64 B contiguous aligned in pair-major hbuf. Wave w covers pairs
  //      [16w, 16w+16) == member w's slice -> wave mid skips polling. ----
  const int p_ld  = tid >> 2;
  const int b0_ld = (tid & 3) * 8;
  const uint32x2* ld_base = hbuf + ((long)gid * PAIRS + p_ld) * BATCH_G + b0_ld;

  // ---- producer store: pair = mid*16 + rg*4 + rt*2 + (quad>>1), batch from l15
  //      -> lanes l15 contiguous => 128 B runs, full sectors. ----
  uint32x2* st_base = hbuf + ((long)gid * PAIRS + mid * 16 + rg * 4 + (quad >> 1)) * BATCH_G + batch;
  const long buf_stride = (long)NGROUP * PAIRS * BATCH_G;
  const bool own_wave = (wv == mid);

  // ---- sc0 coherence probe on buf0 (main loop's tags 1..336 never match MAGIC) ----
  if (!(quad & 1)) {
#pragma unroll
    for (int rt = 0; rt < 2; ++rt) {
      uint32x2 pv; pv[0] = MAGIC; pv[1] = MAGIC;
      st_pair<false>(st_base + rt * 2 * BATCH_G, pv);
    }
  }
  const bool okp = probe_poll(ld_base);
  if (tid == 0) s_ok = 1;
  __syncthreads();
  if (!okp) s_ok = 0;        // benign race: any failing thread forces 0
  __syncthreads();
  if (tid == 0) {
    __hip_atomic_store(&vslot[gid * 8 + mid], (unsigned)(s_ok ? 2 : 1),
                       __ATOMIC_RELEASE, __HIP_MEMORY_SCOPE_AGENT);
    int verdict = 0;
    for (int itr = 0; itr < (1 << 24); ++itr) {
      bool all = true, good = true;
#pragma unroll
      for (int m = 0; m < 8; ++m) {
        unsigned v = __hip_atomic_load(&vslot[gid * 8 + m], __ATOMIC_ACQUIRE,
                                       __HIP_MEMORY_SCOPE_AGENT);
        all &= (v != 0u);
        good &= (v == 2u);
      }
      if (all) { verdict = good ? 1 : 0; break; }
      __builtin_amdgcn_s_sleep(4);
    }
    s_same = verdict;
  }
  __syncthreads();
  const bool same_xcd = (s_same != 0);

  // ---- x prefetch one step ahead (HBM latency off the critical path) ----
  float4 xv = *(const float4*)xrow;     // row for t=1

  for (int t = 1; t <= T_STEPS; ++t) {
    unsigned short* vbuf = v_lds[t & 1];

    // ---- stage prefetched x_t, then issue the next row's load ----
    {
      ushort4 xb;
      xb.x = f2bf(xv.x); xb.y = f2bf(xv.y); xb.z = f2bf(xv.z); xb.w = f2bf(xv.w);
      *(ushort4*)&vbuf[b_stage * VSTRIDE + x_i4] = xb;
    }
    if (t < T_STEPS) xv = *(const float4*)(xrow + (long)t * I_DIM);

    // ---- stage h_{t-1} ----
    unsigned short* hdst = vbuf + b0_ld * VSTRIDE + I_DIM + 2 * p_ld;
    if (t > 1) {
      if (!own_wave) {   // own slice arrived via LDS from our cell lanes
        const unsigned tag = (unsigned)(t - 1);
        const uint32x2* hsrc = ld_base + ((t - 1) & 1) * buf_stride;
        if (same_xcd) stage_h<false>(hsrc, tag, hdst);
        else          stage_h<true >(hsrc, tag, hdst);
      }
    } else {
      // t==1: h_0 = 0 for everyone (incl. own wave)
#pragma unroll
      for (int j = 0; j < 8; ++j) *(unsigned*)(hdst + j * VSTRIDE) = 0u;
    }
    __syncthreads();   // the ONLY barrier per step (v_lds double-buffered)

    // ---- MFMA: 2 row-tiles x 10 k-tiles, B shared across row-tiles ----
    f32x4 acc0 = bias[0], acc1 = bias[1];
    const unsigned short* vb = vbuf + (unsigned)batch * VSTRIDE + quad * 8;
#pragma unroll
    for (int kt = 0; kt < 10; ++kt) {
      bf16x8 bv = __builtin_bit_cast(bf16x8, *(const uint32x4*)(vb + kt * 32));
      acc0 = __builtin_amdgcn_mfma_f32_16x16x32_bf16(afrag[0][kt], bv, acc0, 0, 0, 0);
      acc1 = __builtin_amdgcn_mfma_f32_16x16x32_bf16(afrag[1][kt], bv, acc1, 0, 0, 0);
    }

    // ---- cell fully in registers; own-slice to LDS; tagged pair to global ----
    unsigned short* next_own = v_lds[(t + 1) & 1] + batch * VSTRIDE + I_DIM + mid * 32;
#pragma unroll
    for (int rt = 0; rt < 2; ++rt) {
      const f32x4 acc = rt ? acc1 : acc0;
      float c = sigf(acc[1]) * c_reg[rt] + sigf(acc[0]) * tanhfast(acc[2]);
      float h = sigf(acc[3]) * tanhfast(c);
      c_reg[rt] = c; h_keep[rt] = h;
      unsigned short hb16 = f2bf(h);
      next_own[rg * 8 + rt * 4 + quad] = hb16;                    // LDS shortcut (own WG)
      unsigned hb = (unsigned)hb16;
      unsigned partner = (unsigned)__shfl_xor((int)hb, 16, 64);   // col^1, same batch
      if (!(quad & 1)) {
        uint32x2 pv;
        pv[0] = (unsigned)t;                  // tag
        pv[1] = hb | (partner << 16);         // (col, col+1)
        uint32x2* dst = st_base + rt * 2 * BATCH_G + (t & 1) * buf_stride;
        if (same_xcd) st_pair<false>(dst, pv);   // fire-and-forget, L2-local
        else          st_pair<true >(dst, pv);
      }
    }
  }

  // ---- outputs: h_T then c_T, fp32 (pre-bf16-rounding values) ----
#pragma unroll
  for (int rt = 0; rt < 2; ++rt) {
    int gcol = mid * 32 + rg * 8 + rt * 4 + quad;
    long o = (long)(gid * BATCH_G + batch) * H_DIM + gcol;
    out[o]            = h_keep[rt];
    out[OUT_HALF + o] = c_reg[rt];
  }
}

extern "C" void kernel_launch(void* const* d_in, const int* in_sizes, int n_in,
                              void* d_out, int out_size, void* d_ws, size_t ws_size,
                              hipStream_t stream) {
  const float* x    = (const float*)d_in[0];
  const float* W_ih = (const float*)d_in[1];
  const float* W_hh = (const float*)d_in[2];
  const float* b_ih = (const float*)d_in[3];
  const float* b_hh = (const float*)d_in[4];
  float* out = (float*)d_out;

  uint32x2* hbuf = (uint32x2*)d_ws;   // 2 buffers x 32 groups x 128 pairs x 32 batch x 8 B = 2 MB
  unsigned* xtab = (unsigned*)((char*)d_ws + 2u * NGROUP * PAIRS * BATCH_G * 8u);

  // Clear tags + counters/verdicts so no stale value can match.
  hipMemsetAsync(d_ws, 0, 2u * NGROUP * PAIRS * BATCH_G * 8u + 2048u, stream);
  lstm_persistent<<<dim3(256), dim3(512), 0, stream>>>(x, W_ih, W_hh, b_ih, b_hh, out, hbuf, xtab);
}

// Round 3
// 916.523 us; speedup vs baseline: 1.9044x; 1.9044x over previous
//
#include <hip/hip_runtime.h>
#include <cstdint>

// LSTM: B=1024, T=336, I=64, H=256, gates 4H=1024, K = I+H = 320.
// R8: re-partition to shrink exchange fan-in. 64 batch-groups x 4 member-WGs
// = 256 WGs (1/CU), persistent over all T. Each group owns 16 batches; each
// member owns 64 gate cols (x4 gates). Per step a consumer WG now waits on
// max-of-3 remote producers (was max-of-7): less tail amplification on the
// 336-step serial chain, ~40% less poll traffic, 2/8 waves skip polling.
// Exchange stays device-scope sc0+sc1 (proven correct+fastest; R7 showed
// sc0-only stalls on stale cached lines). Same per-lane registers as R5
// (afrag 80 VGPR), same MFMA/wave, same exchange volume. VSTRIDE back to
// 336 (344 measured worse: conflicts 3.7e7 -> 5.9e7). x prefetched 1 step
// ahead. s_setprio(1) wraps the producer-critical cell+store epilogue.

#define NGROUP  64
#define BATCH_G 16
#define T_STEPS 336
#define I_DIM   64
#define H_DIM   256
#define VSTRIDE 336   // ushorts per staged row: K=320 + 16 pad (672 B, 16B-aligned)
#define PAIRS   128   // h-pairs per batch row (256 cols / 2)
#define OUT_HALF 262144  // 1024*256

typedef __attribute__((ext_vector_type(8))) __bf16 bf16x8;
typedef __attribute__((ext_vector_type(8))) unsigned short ushort8_t;
typedef __attribute__((ext_vector_type(4))) float f32x4;
typedef __attribute__((ext_vector_type(4))) unsigned uint32x4;
typedef __attribute__((ext_vector_type(2))) unsigned uint32x2;

__device__ inline unsigned short f2bf(float f) {
  unsigned u = __builtin_bit_cast(unsigned, f);
  return (unsigned short)((u + 0x7fffu + ((u >> 16) & 1u)) >> 16);
}
__device__ inline float sigf(float x) { return 1.f / (1.f + __expf(-x)); }
__device__ inline float tanhfast(float x) { return 1.f - 2.f / (1.f + __expf(2.f * x)); }

// 2 concurrent coherent 16B loads (4 tagged pairs = 32B contiguous), one round trip.
__device__ inline void ld2_tagged(const uint32x2* p, uint32x4& a, uint32x4& b) {
  asm volatile(
      "global_load_dwordx4 %0, %2, off sc0 sc1\n\t"
      "global_load_dwordx4 %1, %3, off sc0 sc1\n\t"
      "s_waitcnt vmcnt(0)"
      : "=&v"(a), "=&v"(b)
      : "v"(p), "v"(p + 2)
      : "memory");
}
__device__ inline void st_pair(uint32x2* p, uint32x2 v) {
  asm volatile("global_store_dwordx2 %0, %1, off sc0 sc1" :: "v"(p), "v"(v) : "memory");
}

// Poll partner slice until tag matches, then scatter into LDS staging rows.
__device__ inline void stage_h(const uint32x2* hsrc, unsigned tag, unsigned short* hdst) {
  uint32x4 A, Bv;
  int it = 0;
  for (;;) {
    ld2_tagged(hsrc, A, Bv);
    bool ok = (A[0] == tag) & (A[2] == tag) & (Bv[0] == tag) & (Bv[2] == tag);
    if (ok) break;
    if (++it > (1 << 17)) break;   // safety valve vs. hang
    __builtin_amdgcn_s_sleep(1);
  }
  *(unsigned*)(hdst + 0 * VSTRIDE) = A[1];
  *(unsigned*)(hdst + 1 * VSTRIDE) = A[3];
  *(unsigned*)(hdst + 2 * VSTRIDE) = Bv[1];
  *(unsigned*)(hdst + 3 * VSTRIDE) = Bv[3];
}

__global__ __launch_bounds__(512, 2) void lstm_persistent(
    const float* __restrict__ x, const float* __restrict__ W_ih,
    const float* __restrict__ W_hh, const float* __restrict__ b_ih,
    const float* __restrict__ b_hh, float* __restrict__ out,
    uint32x2* __restrict__ hbuf)
{
  __shared__ __align__(16) unsigned short v_lds[2][BATCH_G * VSTRIDE];

  const int tid  = threadIdx.x;
  const int gid  = blockIdx.x & 63;   // batch group (16 batches)
  const int mid  = blockIdx.x >> 6;   // member 0..3 (owns gate cols [mid*64, +64))
  const int wv   = tid >> 6;          // wave 0..7
  const int l    = tid & 63;
  const int l15  = l & 15, quad = l >> 4;
  const int rg   = wv;                // row-group 0..7: local cols [8*rg, +8)

  // ---- A-fragments: local row r16 = l15 -> (gate = l15&3, colfine = l15>>2) ----
  bf16x8 afrag[2][10];
#pragma unroll
  for (int rt = 0; rt < 2; ++rt) {
    int grow = (l15 & 3) * H_DIM + mid * 64 + rg * 8 + rt * 4 + (l15 >> 2);
    const float* wih_row = W_ih + (long)grow * I_DIM;
    const float* whh_row = W_hh + (long)grow * H_DIM;
#pragma unroll
    for (int kt = 0; kt < 10; ++kt) {
      int kbase = kt * 32 + quad * 8;
      ushort8_t a;
#pragma unroll
      for (int e = 0; e < 8; ++e) {
        int k = kbase + e;
        float v = (k < I_DIM) ? wih_row[k] : whh_row[k - I_DIM];
        a[e] = f2bf(v);
      }
      afrag[rt][kt] = __builtin_bit_cast(bf16x8, a);
    }
  }

  // ---- bias as acc-init: lane's cell = (col = rg*8+rt*4+quad, batch = l15) ----
  f32x4 bias[2];
#pragma unroll
  for (int rt = 0; rt < 2; ++rt) {
#pragma unroll
    for (int g = 0; g < 4; ++g) {
      int grow = g * H_DIM + mid * 64 + rg * 8 + rt * 4 + quad;
      bias[rt][g] = b_ih[grow] + b_hh[grow];
    }
  }

  const int batch = l15;              // 0..15 within group
  float c_reg[2] = {0.f, 0.f};
  float h_keep[2];

  // ---- x staging: 32 threads per batch row (float2 each) ----
  const int b_stage = tid >> 5;          // 0..15
  const int x_i2    = (tid & 31) * 2;    // 2 floats of x
  const float* xrow = x + ((long)(gid * BATCH_G + b_stage)) * T_STEPS * I_DIM + x_i2;

  // ---- h staging (consumer): thread owns pair p_ld, batches b0_ld..b0_ld+3
  //      = 32 B contiguous aligned in pair-major hbuf. Wave w covers pairs
  //      [16w, 16w+16) == member (w>>1)'s half-slice -> waves 2*mid, 2*mid+1
  //      skip polling (own slice arrives via LDS shortcut). ----
  const int p_ld  = tid >> 2;            // 0..127
  const int b0_ld = (tid & 3) * 4;       // 0,4,8,12
  const uint32x2* ld_base = hbuf + ((long)gid * PAIRS + p_ld) * BATCH_G + b0_ld;

  // ---- producer store: pair = mid*32 + rg*4 + rt*2 + (quad>>1), batch = l15
  //      -> lanes l15 contiguous => 128 B runs, full sectors. ----
  uint32x2* st_base = hbuf + ((long)gid * PAIRS + mid * 32 + rg * 4 + (quad >> 1)) * BATCH_G + batch;
  const long buf_stride = (long)NGROUP * PAIRS * BATCH_G;
  const bool own_wave = ((wv >> 1) == mid);

  // ---- x prefetch one step ahead (HBM latency off the critical path) ----
  float2 xv = *(const float2*)xrow;     // row for t=1

  for (int t = 1; t <= T_STEPS; ++t) {
    unsigned short* vbuf = v_lds[t & 1];

    // ---- stage prefetched x_t, then issue the next row's load ----
    {
      ushort2 xb;
      xb.x = f2bf(xv.x); xb.y = f2bf(xv.y);
      *(ushort2*)&vbuf[b_stage * VSTRIDE + x_i2] = xb;
    }
    if (t < T_STEPS) xv = *(const float2*)(xrow + (long)t * I_DIM);

    // ---- stage h_{t-1} ----
    unsigned short* hdst = vbuf + b0_ld * VSTRIDE + I_DIM + 2 * p_ld;
    if (t > 1) {
      if (!own_wave) {   // own slice arrived via LDS from our cell lanes
        const unsigned tag = (unsigned)(t - 1);
        const uint32x2* hsrc = ld_base + ((t - 1) & 1) * buf_stride;
        stage_h(hsrc, tag, hdst);
      }
    } else {
      // t==1: h_0 = 0 for everyone (incl. own waves)
#pragma unroll
      for (int j = 0; j < 4; ++j) *(unsigned*)(hdst + j * VSTRIDE) = 0u;
    }
    __syncthreads();   // the ONLY barrier per step (v_lds double-buffered)

    // ---- MFMA: 2 row-tiles x 10 k-tiles, B shared across row-tiles ----
    f32x4 acc0 = bias[0], acc1 = bias[1];
    const unsigned short* vb = vbuf + (unsigned)batch * VSTRIDE + quad * 8;
#pragma unroll
    for (int kt = 0; kt < 10; ++kt) {
      bf16x8 bv = __builtin_bit_cast(bf16x8, *(const uint32x4*)(vb + kt * 32));
      acc0 = __builtin_amdgcn_mfma_f32_16x16x32_bf16(afrag[0][kt], bv, acc0, 0, 0, 0);
      acc1 = __builtin_amdgcn_mfma_f32_16x16x32_bf16(afrag[1][kt], bv, acc1, 0, 0, 0);
    }

    // ---- cell fully in registers; own-slice to LDS; tagged pair to global.
    //      Producer-critical path: boost wave priority. ----
    __builtin_amdgcn_s_setprio(1);
    unsigned short* next_own = v_lds[(t + 1) & 1] + batch * VSTRIDE + I_DIM + mid * 64;
#pragma unroll
    for (int rt = 0; rt < 2; ++rt) {
      const f32x4 acc = rt ? acc1 : acc0;
      float c = sigf(acc[1]) * c_reg[rt] + sigf(acc[0]) * tanhfast(acc[2]);
      float h = sigf(acc[3]) * tanhfast(c);
      c_reg[rt] = c; h_keep[rt] = h;
      unsigned short hb16 = f2bf(h);
      next_own[rg * 8 + rt * 4 + quad] = hb16;                    // LDS shortcut (own WG)
      unsigned hb = (unsigned)hb16;
      unsigned partner = (unsigned)__shfl_xor((int)hb, 16, 64);   // col^1, same batch
      if (!(quad & 1)) {
        uint32x2 pv;
        pv[0] = (unsigned)t;                  // tag
        pv[1] = hb | (partner << 16);         // (col, col+1)
        st_pair(st_base + rt * 2 * BATCH_G + (t & 1) * buf_stride, pv);  // fire-and-forget
      }
    }
    __builtin_amdgcn_s_setprio(0);
  }

  // ---- outputs: h_T then c_T, fp32 (pre-bf16-rounding values) ----
#pragma unroll
  for (int rt = 0; rt < 2; ++rt) {
    int gcol = mid * 64 + rg * 8 + rt * 4 + quad;
    long o = (long)(gid * BATCH_G + batch) * H_DIM + gcol;
    out[o]            = h_keep[rt];
    out[OUT_HALF + o] = c_reg[rt];
  }
}

extern "C" void kernel_launch(void* const* d_in, const int* in_sizes, int n_in,
                              void* d_out, int out_size, void* d_ws, size_t ws_size,
                              hipStream_t stream) {
  const float* x    = (const float*)d_in[0];
  const float* W_ih = (const float*)d_in[1];
  const float* W_hh = (const float*)d_in[2];
  const float* b_ih = (const float*)d_in[3];
  const float* b_hh = (const float*)d_in[4];
  float* out = (float*)d_out;

  uint32x2* hbuf = (uint32x2*)d_ws;   // 2 buffers x 64 groups x 128 pairs x 16 batch x 8 B = 2 MB

  // Clear tags so no stale value can match t in [1,336].
  hipMemsetAsync(d_ws, 0, 2u * NGROUP * PAIRS * BATCH_G * 8u, stream);
  lstm_persistent<<<dim3(256), dim3(512), 0, stream>>>(x, W_ih, W_hh, b_ih, b_hh, out, hbuf);
}

// Round 4
// 789.271 us; speedup vs baseline: 2.2115x; 1.1612x over previous
//
#include <hip/hip_runtime.h>
#include <cstdint>

// LSTM: B=1024, T=336, I=64, H=256, gates 4H=1024, K = I+H = 320.
// R9: split-phase MFMA on R8's 64x4 partition (64 groups x 4 members, 256
// WGs, 16 batches/group, 64 gate-cols/member). Per step:
//   stage x -> barrier1 -> MFMA local tiles (x0,x1,own-h0,own-h1)
//   -> poll remote h (now ~visible: producers stored one local-phase ago)
//   -> barrier2 -> MFMA 6 remote tiles -> cell -> store.
// Overlaps store-visibility latency with local compute instead of sleeping
// on it. afrag kept in SLOT order (0..3 local, 4..9 remote) so all fragment
// indices are compile-time (no scratch); only LDS offsets are runtime.
// t=1: h-region of buffer 1 pre-zeroed, no polling. Exchange stays proven
// device-scope sc0+sc1. x prefetched 1 step ahead. setprio(1) on epilogue.

#define NGROUP  64
#define BATCH_G 16
#define T_STEPS 336
#define I_DIM   64
#define H_DIM   256
#define VSTRIDE 336   // ushorts per staged row: K=320 + 16 pad (672 B, 16B-aligned)
#define PAIRS   128   // h-pairs per batch row (256 cols / 2)
#define OUT_HALF 262144  // 1024*256

typedef __attribute__((ext_vector_type(8))) __bf16 bf16x8;
typedef __attribute__((ext_vector_type(8))) unsigned short ushort8_t;
typedef __attribute__((ext_vector_type(4))) float f32x4;
typedef __attribute__((ext_vector_type(4))) unsigned uint32x4;
typedef __attribute__((ext_vector_type(2))) unsigned uint32x2;

__device__ inline unsigned short f2bf(float f) {
  unsigned u = __builtin_bit_cast(unsigned, f);
  return (unsigned short)((u + 0x7fffu + ((u >> 16) & 1u)) >> 16);
}
__device__ inline float sigf(float x) { return 1.f / (1.f + __expf(-x)); }
__device__ inline float tanhfast(float x) { return 1.f - 2.f / (1.f + __expf(2.f * x)); }

// slot s (0..9) -> k-tile index kt (0..9). Slots 0,1 = x tiles; 2,3 = own h
// tiles (kt = 2+2*mid, 3+2*mid); 4..9 = the 6 remote h tiles in kt order.
__device__ inline int slot_kt(int s, int mid) {
  return (s < 2) ? s
       : (s < 4) ? (2 + 2 * mid + (s - 2))
       : (((s - 4) < 2 * mid) ? (s - 2) : s);
}

// 2 concurrent coherent 16B loads (4 tagged pairs = 32B contiguous), one round trip.
__device__ inline void ld2_tagged(const uint32x2* p, uint32x4& a, uint32x4& b) {
  asm volatile(
      "global_load_dwordx4 %0, %2, off sc0 sc1\n\t"
      "global_load_dwordx4 %1, %3, off sc0 sc1\n\t"
      "s_waitcnt vmcnt(0)"
      : "=&v"(a), "=&v"(b)
      : "v"(p), "v"(p + 2)
      : "memory");
}
__device__ inline void st_pair(uint32x2* p, uint32x2 v) {
  asm volatile("global_store_dwordx2 %0, %1, off sc0 sc1" :: "v"(p), "v"(v) : "memory");
}

// Poll partner slice until tag matches, then scatter into LDS staging rows.
__device__ inline void stage_h(const uint32x2* hsrc, unsigned tag, unsigned short* hdst) {
  uint32x4 A, Bv;
  int it = 0;
  for (;;) {
    ld2_tagged(hsrc, A, Bv);
    bool ok = (A[0] == tag) & (A[2] == tag) & (Bv[0] == tag) & (Bv[2] == tag);
    if (ok) break;
    if (++it > (1 << 17)) break;   // safety valve vs. hang
    __builtin_amdgcn_s_sleep(1);
  }
  *(unsigned*)(hdst + 0 * VSTRIDE) = A[1];
  *(unsigned*)(hdst + 1 * VSTRIDE) = A[3];
  *(unsigned*)(hdst + 2 * VSTRIDE) = Bv[1];
  *(unsigned*)(hdst + 3 * VSTRIDE) = Bv[3];
}

__global__ __launch_bounds__(512, 2) void lstm_persistent(
    const float* __restrict__ x, const float* __restrict__ W_ih,
    const float* __restrict__ W_hh, const float* __restrict__ b_ih,
    const float* __restrict__ b_hh, float* __restrict__ out,
    uint32x2* __restrict__ hbuf)
{
  __shared__ __align__(16) unsigned short v_lds[2][BATCH_G * VSTRIDE];

  const int tid  = threadIdx.x;
  const int gid  = blockIdx.x & 63;   // batch group (16 batches)
  const int mid  = blockIdx.x >> 6;   // member 0..3 (owns gate cols [mid*64, +64))
  const int wv   = tid >> 6;          // wave 0..7
  const int l    = tid & 63;
  const int l15  = l & 15, quad = l >> 4;
  const int rg   = wv;                // row-group 0..7: local cols [8*rg, +8)

  // ---- A-fragments in SLOT order (0,1=x; 2,3=own h; 4..9=remote h) ----
  bf16x8 afrag[2][10];
#pragma unroll
  for (int rt = 0; rt < 2; ++rt) {
    int grow = (l15 & 3) * H_DIM + mid * 64 + rg * 8 + rt * 4 + (l15 >> 2);
    const float* wih_row = W_ih + (long)grow * I_DIM;
    const float* whh_row = W_hh + (long)grow * H_DIM;
#pragma unroll
    for (int s = 0; s < 10; ++s) {
      int kt = slot_kt(s, mid);
      int kbase = kt * 32 + quad * 8;
      ushort8_t a;
#pragma unroll
      for (int e = 0; e < 8; ++e) {
        int k = kbase + e;
        float v = (k < I_DIM) ? wih_row[k] : whh_row[k - I_DIM];
        a[e] = f2bf(v);
      }
      afrag[rt][s] = __builtin_bit_cast(bf16x8, a);
    }
  }

  // ---- bias as acc-init: lane's cell = (col = rg*8+rt*4+quad, batch = l15) ----
  f32x4 bias[2];
#pragma unroll
  for (int rt = 0; rt < 2; ++rt) {
#pragma unroll
    for (int g = 0; g < 4; ++g) {
      int grow = g * H_DIM + mid * 64 + rg * 8 + rt * 4 + quad;
      bias[rt][g] = b_ih[grow] + b_hh[grow];
    }
  }

  const int batch = l15;              // 0..15 within group
  float c_reg[2] = {0.f, 0.f};
  float h_keep[2];

  // ---- x staging: 32 threads per batch row (float2 each) ----
  const int b_stage = tid >> 5;          // 0..15
  const int x_i2    = (tid & 31) * 2;    // 2 floats of x
  const float* xrow = x + ((long)(gid * BATCH_G + b_stage)) * T_STEPS * I_DIM + x_i2;

  // ---- h staging (consumer): thread owns pair p_ld, batches b0_ld..b0_ld+3
  //      = 32 B contiguous aligned in pair-major hbuf. Wave w covers pairs
  //      [16w, 16w+16) == member (w>>1)'s half-slice -> waves 2*mid, 2*mid+1
  //      skip polling (own slice arrives via LDS shortcut). ----
  const int p_ld  = tid >> 2;            // 0..127
  const int b0_ld = (tid & 3) * 4;       // 0,4,8,12
  const uint32x2* ld_base = hbuf + ((long)gid * PAIRS + p_ld) * BATCH_G + b0_ld;

  // ---- producer store: pair = mid*32 + rg*4 + rt*2 + (quad>>1), batch = l15
  //      -> lanes l15 contiguous => 128 B runs, full sectors. ----
  uint32x2* st_base = hbuf + ((long)gid * PAIRS + mid * 32 + rg * 4 + (quad >> 1)) * BATCH_G + batch;
  const long buf_stride = (long)NGROUP * PAIRS * BATCH_G;
  const bool own_wave = ((wv >> 1) == mid);

  // ---- pre-zero h region of buffer 1 (t=1 reads zeros; no polling at t=1).
  //      512 threads x 16 B == 16 rows x 512 B exactly. ----
  {
    int zr = tid >> 5, zc = (tid & 31) * 8;
    uint32x4 z = {0u, 0u, 0u, 0u};
    *(uint32x4*)&v_lds[1][zr * VSTRIDE + I_DIM + zc] = z;
  }

  // ---- x prefetch one step ahead (HBM latency off the critical path) ----
  float2 xv = *(const float2*)xrow;     // row for t=1

  for (int t = 1; t <= T_STEPS; ++t) {
    unsigned short* vbuf = v_lds[t & 1];

    // ---- stage prefetched x_t, then issue the next row's load ----
    {
      ushort2 xb;
      xb.x = f2bf(xv.x); xb.y = f2bf(xv.y);
      *(ushort2*)&vbuf[b_stage * VSTRIDE + x_i2] = xb;
    }
    if (t < T_STEPS) xv = *(const float2*)(xrow + (long)t * I_DIM);

    __syncthreads();   // barrier1: x_t + own-h (from prev epilogue) visible

    // ---- phase 1: local tiles (x0, x1, own-h0, own-h1) ----
    f32x4 acc0 = bias[0], acc1 = bias[1];
    const unsigned short* vb = vbuf + (unsigned)batch * VSTRIDE + quad * 8;
#pragma unroll
    for (int s = 0; s < 4; ++s) {
      int kt = slot_kt(s, mid);
      bf16x8 bv = __builtin_bit_cast(bf16x8, *(const uint32x4*)(vb + kt * 32));
      acc0 = __builtin_amdgcn_mfma_f32_16x16x32_bf16(afrag[0][s], bv, acc0, 0, 0, 0);
      acc1 = __builtin_amdgcn_mfma_f32_16x16x32_bf16(afrag[1][s], bv, acc1, 0, 0, 0);
    }

    // ---- poll + stage remote h_{t-1} (producers stored it ~1 phase ago) ----
    if (t > 1 && !own_wave) {
      unsigned short* hdst = vbuf + b0_ld * VSTRIDE + I_DIM + 2 * p_ld;
      const uint32x2* hsrc = ld_base + ((t - 1) & 1) * buf_stride;
      stage_h(hsrc, (unsigned)(t - 1), hdst);
    }
    __syncthreads();   // barrier2: remote h staged

    // ---- phase 2: 6 remote tiles ----
#pragma unroll
    for (int s = 4; s < 10; ++s) {
      int kt = slot_kt(s, mid);
      bf16x8 bv = __builtin_bit_cast(bf16x8, *(const uint32x4*)(vb + kt * 32));
      acc0 = __builtin_amdgcn_mfma_f32_16x16x32_bf16(afrag[0][s], bv, acc0, 0, 0, 0);
      acc1 = __builtin_amdgcn_mfma_f32_16x16x32_bf16(afrag[1][s], bv, acc1, 0, 0, 0);
    }

    // ---- cell fully in registers; own-slice to LDS; tagged pair to global.
    //      Producer-critical path: boost wave priority. ----
    __builtin_amdgcn_s_setprio(1);
    unsigned short* next_own = v_lds[(t + 1) & 1] + batch * VSTRIDE + I_DIM + mid * 64;
#pragma unroll
    for (int rt = 0; rt < 2; ++rt) {
      const f32x4 acc = rt ? acc1 : acc0;
      float c = sigf(acc[1]) * c_reg[rt] + sigf(acc[0]) * tanhfast(acc[2]);
      float h = sigf(acc[3]) * tanhfast(c);
      c_reg[rt] = c; h_keep[rt] = h;
      unsigned short hb16 = f2bf(h);
      next_own[rg * 8 + rt * 4 + quad] = hb16;                    // LDS shortcut (own WG)
      unsigned hb = (unsigned)hb16;
      unsigned partner = (unsigned)__shfl_xor((int)hb, 16, 64);   // col^1, same batch
      if (!(quad & 1)) {
        uint32x2 pv;
        pv[0] = (unsigned)t;                  // tag
        pv[1] = hb | (partner << 16);         // (col, col+1)
        st_pair(st_base + rt * 2 * BATCH_G + (t & 1) * buf_stride, pv);  // fire-and-forget
      }
    }
    __builtin_amdgcn_s_setprio(0);
  }

  // ---- outputs: h_T then c_T, fp32 (pre-bf16-rounding values) ----
#pragma unroll
  for (int rt = 0; rt < 2; ++rt) {
    int gcol = mid * 64 + rg * 8 + rt * 4 + quad;
    long o = (long)(gid * BATCH_G + batch) * H_DIM + gcol;
    out[o]            = h_keep[rt];
    out[OUT_HALF + o] = c_reg[rt];
  }
}

extern "C" void kernel_launch(void* const* d_in, const int* in_sizes, int n_in,
                              void* d_out, int out_size, void* d_ws, size_t ws_size,
                              hipStream_t stream) {
  const float* x    = (const float*)d_in[0];
  const float* W_ih = (const float*)d_in[1];
  const float* W_hh = (const float*)d_in[2];
  const float* b_ih = (const float*)d_in[3];
  const float* b_hh = (const float*)d_in[4];
  float* out = (float*)d_out;

  uint32x2* hbuf = (uint32x2*)d_ws;   // 2 buffers x 64 groups x 128 pairs x 16 batch x 8 B = 2 MB

  // Clear tags so no stale value can match t in [1,336].
  hipMemsetAsync(d_ws, 0, 2u * NGROUP * PAIRS * BATCH_G * 8u, stream);
  lstm_persistent<<<dim3(256), dim3(512), 0, stream>>>(x, W_ih, W_hh, b_ih, b_hh, out, hbuf);
}